// Round 1
// baseline (3304.314 us; speedup 1.0000x reference)
//
#include <hip/hip_runtime.h>
#include <math.h>

// ---------------------------------------------------------------------------
// DDI_GraphTransformer: 2x TransformerConv(H=8, C=16, D=128), N=50000, E=800000
// Layer: Q/K/V/S = X@W+b ; alpha = <Q[dst],K[src]>*0.25 per head ;
//        segment-softmax over dst ; out = seg_sum(a*V[src]) + S ; relu (L1 only)
// ---------------------------------------------------------------------------

#define HEADS 8
#define CH 16
#define DM 128           // HEADS*CH
#define SCALE 0.25f      // 1/sqrt(16)

// ---------------- float -> orderable-uint encoding for atomic segment-max ---
// enc is monotone: f1 < f2  <=>  enc(f1) < enc(f2); enc(any real) > 0, so a
// zero-initialized m_enc acts as -inf identity.
static __device__ __forceinline__ unsigned enc_f32(float f) {
    unsigned u = __float_as_uint(f);
    return (u & 0x80000000u) ? ~u : (u | 0x80000000u);
}
static __device__ __forceinline__ float dec_f32(unsigned u) {
    return (u & 0x80000000u) ? __uint_as_float(u & 0x7FFFFFFFu)
                             : __uint_as_float(~u);
}

static __device__ __forceinline__ void atom_add_f32(float* p, float v) {
    // native global_atomic_add_f32 on gfx950 (device scope); denorm flush is
    // irrelevant at our magnitudes
    unsafeAtomicAdd(p, v);
}

// ---------------- fused linear: Q/K/V/S = X @ W + b -------------------------
// grid.x = ceil(N/64) row blocks, grid.y = 8 (4 matrices x 2 col-halves of 64)
#define BM 64
#define BN 64
#define BK 16

__global__ __launch_bounds__(256)
void gemm_qkvs(const float* __restrict__ X,
               const float* __restrict__ Wq, const float* __restrict__ Wk,
               const float* __restrict__ Wv, const float* __restrict__ Wsk,
               const float* __restrict__ bq, const float* __restrict__ bk,
               const float* __restrict__ bv, const float* __restrict__ bsk,
               float* __restrict__ Qo, float* __restrict__ Ko,
               float* __restrict__ Vo, float* __restrict__ Yo,
               int N)
{
    __shared__ float Xs[BK][BM];   // [k][m]
    __shared__ float Wt[BK][BN];   // [k][n]

    const int by  = blockIdx.y;        // 0..7
    const int mat = by >> 1;           // 0..3 -> Q,K,V,S
    const float* W  = (mat == 0) ? Wq : (mat == 1) ? Wk : (mat == 2) ? Wv : Wsk;
    const float* Bv = (mat == 0) ? bq : (mat == 1) ? bk : (mat == 2) ? bv : bsk;
    float*       Out = (mat == 0) ? Qo : (mat == 1) ? Ko : (mat == 2) ? Vo : Yo;
    const int colBase = (by & 1) * BN; // 0 or 64 inside the 128-wide matrix

    const int row0 = blockIdx.x * BM;
    const int tid  = threadIdx.x;
    const int tx   = tid & 15;   // col group
    const int ty   = tid >> 4;   // row group
    float acc[4][4] = {{0.f}};

    for (int k0 = 0; k0 < DM; k0 += BK) {
        // stage X tile (64 rows x 16 k), transposed into Xs[k][m]
        {
            int r  = tid >> 2;           // 0..63
            int c4 = (tid & 3) * 4;      // 0,4,8,12
            int row = row0 + r;
            float4 xv = make_float4(0.f, 0.f, 0.f, 0.f);
            if (row < N) xv = *(const float4*)(X + (size_t)row * DM + k0 + c4);
            Xs[c4 + 0][r] = xv.x; Xs[c4 + 1][r] = xv.y;
            Xs[c4 + 2][r] = xv.z; Xs[c4 + 3][r] = xv.w;
        }
        // stage W tile (16 k x 64 cols)
        {
            int kk = tid >> 4;           // 0..15
            int c4 = (tid & 15) * 4;     // 0..60
            float4 wv = *(const float4*)(W + (size_t)(k0 + kk) * DM + colBase + c4);
            Wt[kk][c4 + 0] = wv.x; Wt[kk][c4 + 1] = wv.y;
            Wt[kk][c4 + 2] = wv.z; Wt[kk][c4 + 3] = wv.w;
        }
        __syncthreads();
        #pragma unroll
        for (int kk = 0; kk < BK; ++kk) {
            float4 av = *(const float4*)&Xs[kk][ty * 4];
            float4 bv = *(const float4*)&Wt[kk][tx * 4];
            float a[4] = {av.x, av.y, av.z, av.w};
            float b[4] = {bv.x, bv.y, bv.z, bv.w};
            #pragma unroll
            for (int i = 0; i < 4; ++i)
                #pragma unroll
                for (int j = 0; j < 4; ++j)
                    acc[i][j] = fmaf(a[i], b[j], acc[i][j]);
        }
        __syncthreads();
    }

    const int c = colBase + tx * 4;
    #pragma unroll
    for (int i = 0; i < 4; ++i) {
        int row = row0 + ty * 4 + i;
        if (row < N) {
            float4 o;
            o.x = acc[i][0] + Bv[c + 0];
            o.y = acc[i][1] + Bv[c + 1];
            o.z = acc[i][2] + Bv[c + 2];
            o.w = acc[i][3] + Bv[c + 3];
            *(float4*)(Out + (size_t)row * DM + c) = o;
        }
    }
}

// ---------------- edge pass A: alpha + segment-max ---------------------------
// one thread per (edge, head)
__global__ __launch_bounds__(256)
void edge_alpha(const float* __restrict__ Q, const float* __restrict__ K,
                const int* __restrict__ src, const int* __restrict__ dst,
                float* __restrict__ alpha, unsigned* __restrict__ m_enc, int E)
{
    int idx = blockIdx.x * blockDim.x + threadIdx.x;
    if (idx >= E * HEADS) return;
    int e = idx >> 3, h = idx & 7;
    int s = src[e], d = dst[e];
    const float4* qp = (const float4*)(Q + (size_t)d * DM + h * CH);
    const float4* kp = (const float4*)(K + (size_t)s * DM + h * CH);
    float acc = 0.f;
    #pragma unroll
    for (int i = 0; i < 4; ++i) {
        float4 a = qp[i], b = kp[i];
        acc += a.x * b.x + a.y * b.y + a.z * b.z + a.w * b.w;
    }
    float al = acc * SCALE;
    alpha[idx] = al;
    atomicMax(&m_enc[(size_t)d * HEADS + h], enc_f32(al));
}

// ---------------- edge pass B: exp + segment-sum(denom) ----------------------
__global__ __launch_bounds__(256)
void edge_exp(float* __restrict__ alpha, const unsigned* __restrict__ m_enc,
              float* __restrict__ denom, const int* __restrict__ dst, int E)
{
    int idx = blockIdx.x * blockDim.x + threadIdx.x;
    if (idx >= E * HEADS) return;
    int e = idx >> 3, h = idx & 7;
    int d = dst[e];
    float m = dec_f32(m_enc[(size_t)d * HEADS + h]);
    float a = __expf(alpha[idx] - m);
    alpha[idx] = a;                       // overwrite with un-normalized weight
    atom_add_f32(&denom[(size_t)d * HEADS + h], a);
}

// ---------------- edge pass C: scatter a*V[src] into ACC ---------------------
// one thread per (edge, 4-float group): 32 threads/edge
__global__ __launch_bounds__(256)
void edge_msg(const float* __restrict__ V, const float* __restrict__ alpha,
              const int* __restrict__ src, const int* __restrict__ dst,
              float* __restrict__ ACC, int E)
{
    int t = blockIdx.x * blockDim.x + threadIdx.x;
    if (t >= E * 32) return;
    int e  = t >> 5;
    int c4 = (t & 31) * 4;
    int h  = c4 >> 4;
    int s = src[e], d = dst[e];
    float a = alpha[(size_t)e * HEADS + h];
    float4 v = *(const float4*)(V + (size_t)s * DM + c4);
    float* base = ACC + (size_t)d * DM + c4;
    atom_add_f32(base + 0, v.x * a);
    atom_add_f32(base + 1, v.y * a);
    atom_add_f32(base + 2, v.z * a);
    atom_add_f32(base + 3, v.w * a);
}

// ---------------- finalize: Y = ACC/denom + skip(Y), optional relu -----------
__global__ __launch_bounds__(256)
void finalize_k(const float* __restrict__ ACC, const float* __restrict__ denom,
                float* __restrict__ Y, int N, int relu)
{
    int t = blockIdx.x * blockDim.x + threadIdx.x;
    if (t >= N * 32) return;
    int n  = t >> 5;
    int c4 = (t & 31) * 4;
    int h  = c4 >> 4;
    float den = denom[(size_t)n * HEADS + h];
    float inv = den > 0.f ? 1.f / den : 0.f;
    float4 a = *(const float4*)(ACC + (size_t)n * DM + c4);
    float4 y = *(const float4*)(Y + (size_t)n * DM + c4);
    y.x += a.x * inv; y.y += a.y * inv; y.z += a.z * inv; y.w += a.w * inv;
    if (relu) {
        y.x = fmaxf(y.x, 0.f); y.y = fmaxf(y.y, 0.f);
        y.z = fmaxf(y.z, 0.f); y.w = fmaxf(y.w, 0.f);
    }
    *(float4*)(Y + (size_t)n * DM + c4) = y;
}

// ---------------------------------------------------------------------------
static void run_layer(const float* X, float* Y,
                      const float* Wq, const float* bq,
                      const float* Wk, const float* bk,
                      const float* Wv, const float* bv,
                      const float* Wsk, const float* bsk,
                      float* Q, float* K, float* V, float* ACC,
                      float* alpha, float* denom, unsigned* m_enc,
                      const int* src, const int* dst,
                      int N, int E, int relu, hipStream_t stream)
{
    dim3 ggrid((N + BM - 1) / BM, 8);
    gemm_qkvs<<<ggrid, 256, 0, stream>>>(X, Wq, Wk, Wv, Wsk, bq, bk, bv, bsk,
                                         Q, K, V, Y, N);
    hipMemsetAsync(m_enc, 0, (size_t)N * HEADS * sizeof(unsigned), stream);
    hipMemsetAsync(denom, 0, (size_t)N * HEADS * sizeof(float), stream);
    hipMemsetAsync(ACC, 0, (size_t)N * DM * sizeof(float), stream);

    int e8 = E * HEADS;
    edge_alpha<<<(e8 + 255) / 256, 256, 0, stream>>>(Q, K, src, dst, alpha, m_enc, E);
    edge_exp<<<(e8 + 255) / 256, 256, 0, stream>>>(alpha, m_enc, denom, dst, E);
    int e32 = E * 32;
    edge_msg<<<(e32 + 255) / 256, 256, 0, stream>>>(V, alpha, src, dst, ACC, E);
    int n32 = N * 32;
    finalize_k<<<(n32 + 255) / 256, 256, 0, stream>>>(ACC, denom, Y, N, relu);
}

extern "C" void kernel_launch(void* const* d_in, const int* in_sizes, int n_in,
                              void* d_out, int out_size, void* d_ws, size_t ws_size,
                              hipStream_t stream)
{
    const float* x   = (const float*)d_in[0];
    const int* eidx  = (const int*)d_in[1];   // [2, E] int32
    // d_in[2] edge_attr: unused by the reference forward
    const float* qw0 = (const float*)d_in[3];  const float* qb0 = (const float*)d_in[4];
    const float* kw0 = (const float*)d_in[5];  const float* kb0 = (const float*)d_in[6];
    const float* vw0 = (const float*)d_in[7];  const float* vb0 = (const float*)d_in[8];
    const float* sw0 = (const float*)d_in[9];  const float* sb0 = (const float*)d_in[10];
    const float* qw1 = (const float*)d_in[11]; const float* qb1 = (const float*)d_in[12];
    const float* kw1 = (const float*)d_in[13]; const float* kb1 = (const float*)d_in[14];
    const float* vw1 = (const float*)d_in[15]; const float* vb1 = (const float*)d_in[16];
    const float* sw1 = (const float*)d_in[17]; const float* sb1 = (const float*)d_in[18];

    const int N = in_sizes[0] / DM;
    const int E = in_sizes[1] / 2;
    const int* src = eidx;
    const int* dst = eidx + E;

    // workspace layout (floats): Q,K,V,ACC,H1 [N*128 each] | alpha [E*8]
    //                            | denom [N*8] | m_enc [N*8 uints]
    float* ws    = (float*)d_ws;
    size_t nd    = (size_t)N * DM;
    float* Q     = ws;
    float* K     = Q + nd;
    float* V     = K + nd;
    float* ACC   = V + nd;
    float* H1    = ACC + nd;
    float* alpha = H1 + nd;
    float* denom = alpha + (size_t)E * HEADS;
    unsigned* m_enc = (unsigned*)(denom + (size_t)N * HEADS);

    float* out = (float*)d_out;

    // layer 1: x -> H1 (with relu)
    run_layer(x, H1, qw0, qb0, kw0, kb0, vw0, vb0, sw0, sb0,
              Q, K, V, ACC, alpha, denom, m_enc, src, dst, N, E, 1, stream);
    // layer 2: H1 -> out (no relu)
    run_layer(H1, out, qw1, qb1, kw1, kb1, vw1, vb1, sw1, sb1,
              Q, K, V, ACC, alpha, denom, m_enc, src, dst, N, E, 0, stream);
}

// Round 2
// 720.550 us; speedup vs baseline: 4.5858x; 4.5858x over previous
//
#include <hip/hip_runtime.h>
#include <math.h>

// ---------------------------------------------------------------------------
// DDI_GraphTransformer: 2x TransformerConv(H=8, C=16, D=128), N=50000, E=800000
// R1: replace edge-space atomic scatter (edge_msg: 1340us, VALUBusy 1.3%) with
//     per-call CSR build + per-node fused online-softmax aggregation (no
//     float atomics at all).
// ---------------------------------------------------------------------------

#define HEADS 8
#define CH 16
#define DM 128           // HEADS*CH
#define SCALE 0.25f      // 1/sqrt(16)

// ---------------- fused linear: Q/K/V/S = X @ W + b -------------------------
// grid.x = ceil(N/64) row blocks, grid.y = 8 (4 matrices x 2 col-halves of 64)
#define BM 64
#define BN 64
#define BK 16

__global__ __launch_bounds__(256)
void gemm_qkvs(const float* __restrict__ X,
               const float* __restrict__ Wq, const float* __restrict__ Wk,
               const float* __restrict__ Wv, const float* __restrict__ Wsk,
               const float* __restrict__ bq, const float* __restrict__ bk,
               const float* __restrict__ bv, const float* __restrict__ bsk,
               float* __restrict__ Qo, float* __restrict__ Ko,
               float* __restrict__ Vo, float* __restrict__ Yo,
               int N)
{
    __shared__ float Xs[BK][BM];   // [k][m]
    __shared__ float Wt[BK][BN];   // [k][n]

    const int by  = blockIdx.y;        // 0..7
    const int mat = by >> 1;           // 0..3 -> Q,K,V,S
    const float* W  = (mat == 0) ? Wq : (mat == 1) ? Wk : (mat == 2) ? Wv : Wsk;
    const float* Bv = (mat == 0) ? bq : (mat == 1) ? bk : (mat == 2) ? bv : bsk;
    float*       Out = (mat == 0) ? Qo : (mat == 1) ? Ko : (mat == 2) ? Vo : Yo;
    const int colBase = (by & 1) * BN; // 0 or 64 inside the 128-wide matrix

    const int row0 = blockIdx.x * BM;
    const int tid  = threadIdx.x;
    const int tx   = tid & 15;   // col group
    const int ty   = tid >> 4;   // row group
    float acc[4][4] = {{0.f}};

    for (int k0 = 0; k0 < DM; k0 += BK) {
        // stage X tile (64 rows x 16 k), transposed into Xs[k][m]
        {
            int r  = tid >> 2;           // 0..63
            int c4 = (tid & 3) * 4;      // 0,4,8,12
            int row = row0 + r;
            float4 xv = make_float4(0.f, 0.f, 0.f, 0.f);
            if (row < N) xv = *(const float4*)(X + (size_t)row * DM + k0 + c4);
            Xs[c4 + 0][r] = xv.x; Xs[c4 + 1][r] = xv.y;
            Xs[c4 + 2][r] = xv.z; Xs[c4 + 3][r] = xv.w;
        }
        // stage W tile (16 k x 64 cols)
        {
            int kk = tid >> 4;           // 0..15
            int c4 = (tid & 15) * 4;     // 0..60
            float4 wv = *(const float4*)(W + (size_t)(k0 + kk) * DM + colBase + c4);
            Wt[kk][c4 + 0] = wv.x; Wt[kk][c4 + 1] = wv.y;
            Wt[kk][c4 + 2] = wv.z; Wt[kk][c4 + 3] = wv.w;
        }
        __syncthreads();
        #pragma unroll
        for (int kk = 0; kk < BK; ++kk) {
            float4 av = *(const float4*)&Xs[kk][ty * 4];
            float4 bv = *(const float4*)&Wt[kk][tx * 4];
            float a[4] = {av.x, av.y, av.z, av.w};
            float b[4] = {bv.x, bv.y, bv.z, bv.w};
            #pragma unroll
            for (int i = 0; i < 4; ++i)
                #pragma unroll
                for (int j = 0; j < 4; ++j)
                    acc[i][j] = fmaf(a[i], b[j], acc[i][j]);
        }
        __syncthreads();
    }

    const int c = colBase + tx * 4;
    #pragma unroll
    for (int i = 0; i < 4; ++i) {
        int row = row0 + ty * 4 + i;
        if (row < N) {
            float4 o;
            o.x = acc[i][0] + Bv[c + 0];
            o.y = acc[i][1] + Bv[c + 1];
            o.z = acc[i][2] + Bv[c + 2];
            o.w = acc[i][3] + Bv[c + 3];
            *(float4*)(Out + (size_t)row * DM + c) = o;
        }
    }
}

// ---------------- CSR build: histogram -> scan -> scatter --------------------
__global__ __launch_bounds__(256)
void hist_k(const int* __restrict__ dst, int* __restrict__ counts, int E)
{
    int e = blockIdx.x * blockDim.x + threadIdx.x;
    if (e < E) atomicAdd(&counts[dst[e]], 1);
}

// single-block exclusive scan of counts[0..N) -> rowptr[0..N]
__global__ __launch_bounds__(1024)
void scan_k(const int* __restrict__ counts, int* __restrict__ rowptr, int N)
{
    __shared__ int sdata[1024];
    const int t = threadIdx.x;
    const int chunk = (N + 1023) / 1024;
    const int begin = t * chunk;
    const int end   = min(begin + chunk, N);
    int sum = 0;
    for (int i = begin; i < end; ++i) sum += counts[i];
    sdata[t] = sum;
    __syncthreads();
    // Hillis-Steele inclusive scan over the 1024 per-thread totals
    for (int off = 1; off < 1024; off <<= 1) {
        int v = (t >= off) ? sdata[t - off] : 0;
        __syncthreads();
        if (t >= off) sdata[t] += v;
        __syncthreads();
    }
    int run = (t == 0) ? 0 : sdata[t - 1];  // exclusive prefix of this chunk
    for (int i = begin; i < end; ++i) {
        rowptr[i] = run;
        run += counts[i];
    }
    if (t == 0) rowptr[N] = sdata[1023];
}

__global__ __launch_bounds__(256)
void scatter_k(const int* __restrict__ src, const int* __restrict__ dst,
               int* __restrict__ cursor, int* __restrict__ esrc, int E)
{
    int e = blockIdx.x * blockDim.x + threadIdx.x;
    if (e >= E) return;
    int pos = atomicAdd(&cursor[dst[e]], 1);
    esrc[pos] = src[e];
}

// ---------------- fused per-node attention aggregation -----------------------
// one block (128 threads = one channel each) per dst node; online softmax over
// the node's incoming edges; 16-lane shuffle reduction for per-head dots.
__global__ __launch_bounds__(128)
void node_attn(const float* __restrict__ Q, const float* __restrict__ K,
               const float* __restrict__ V,
               const int* __restrict__ rowptr, const int* __restrict__ esrc,
               float* __restrict__ Y, int N, int relu)
{
    const int n = blockIdx.x;
    if (n >= N) return;
    const int c = threadIdx.x;               // channel 0..127; head = c>>4
    const float q = Q[(size_t)n * DM + c];
    const int beg = rowptr[n], end = rowptr[n + 1];

    float m = -INFINITY, l = 0.f, acc = 0.f;
    for (int i = beg; i < end; ++i) {
        const int s = esrc[i];
        const float k = K[(size_t)s * DM + c];
        const float v = V[(size_t)s * DM + c];
        float p = q * k;
        p += __shfl_xor(p, 1, 16);
        p += __shfl_xor(p, 2, 16);
        p += __shfl_xor(p, 4, 16);
        p += __shfl_xor(p, 8, 16);
        p *= SCALE;                           // alpha for this (edge, head)
        const float nm = fmaxf(m, p);
        const float so = __expf(m - nm);      // 0 on first edge (m = -inf)
        const float w  = __expf(p - nm);
        l   = l * so + w;
        acc = acc * so + w * v;
        m = nm;
    }
    const float inv = (l > 0.f) ? 1.f / l : 0.f;  // deg==0 -> skip only
    float y = Y[(size_t)n * DM + c] + acc * inv;
    if (relu) y = fmaxf(y, 0.f);
    Y[(size_t)n * DM + c] = y;
}

// ---------------------------------------------------------------------------
extern "C" void kernel_launch(void* const* d_in, const int* in_sizes, int n_in,
                              void* d_out, int out_size, void* d_ws, size_t ws_size,
                              hipStream_t stream)
{
    const float* x   = (const float*)d_in[0];
    const int* eidx  = (const int*)d_in[1];   // [2, E]
    const float* qw0 = (const float*)d_in[3];  const float* qb0 = (const float*)d_in[4];
    const float* kw0 = (const float*)d_in[5];  const float* kb0 = (const float*)d_in[6];
    const float* vw0 = (const float*)d_in[7];  const float* vb0 = (const float*)d_in[8];
    const float* sw0 = (const float*)d_in[9];  const float* sb0 = (const float*)d_in[10];
    const float* qw1 = (const float*)d_in[11]; const float* qb1 = (const float*)d_in[12];
    const float* kw1 = (const float*)d_in[13]; const float* kb1 = (const float*)d_in[14];
    const float* vw1 = (const float*)d_in[15]; const float* vb1 = (const float*)d_in[16];
    const float* sw1 = (const float*)d_in[17]; const float* sb1 = (const float*)d_in[18];

    const int N = in_sizes[0] / DM;
    const int E = in_sizes[1] / 2;
    const int* src = eidx;
    const int* dst = eidx + E;

    // workspace: Q,K,V,H1 [N*128 f32] | counts[N] rowptr[N+1] cursor[N] esrc[E]
    float* ws  = (float*)d_ws;
    size_t nd  = (size_t)N * DM;
    float* Q   = ws;
    float* K   = Q + nd;
    float* V   = K + nd;
    float* H1  = V + nd;
    int* counts = (int*)(H1 + nd);
    int* rowptr = counts + N;
    int* cursor = rowptr + (N + 1);
    int* esrc   = cursor + N;
    float* out  = (float*)d_out;

    // ---- CSR build (edges identical for both layers; rebuilt every call) ----
    hipMemsetAsync(counts, 0, (size_t)N * sizeof(int), stream);
    hist_k<<<(E + 255) / 256, 256, 0, stream>>>(dst, counts, E);
    scan_k<<<1, 1024, 0, stream>>>(counts, rowptr, N);
    hipMemcpyAsync(cursor, rowptr, (size_t)N * sizeof(int),
                   hipMemcpyDeviceToDevice, stream);
    scatter_k<<<(E + 255) / 256, 256, 0, stream>>>(src, dst, cursor, esrc, E);

    dim3 ggrid((N + BM - 1) / BM, 8);

    // ---- layer 1: x -> H1 (relu) ----
    gemm_qkvs<<<ggrid, 256, 0, stream>>>(x, qw0, kw0, vw0, sw0,
                                         qb0, kb0, vb0, sb0, Q, K, V, H1, N);
    node_attn<<<N, 128, 0, stream>>>(Q, K, V, rowptr, esrc, H1, N, 1);

    // ---- layer 2: H1 -> out ----
    gemm_qkvs<<<ggrid, 256, 0, stream>>>(H1, qw1, kw1, vw1, sw1,
                                         qb1, kb1, vb1, sb1, Q, K, V, out, N);
    node_attn<<<N, 128, 0, stream>>>(Q, K, V, rowptr, esrc, out, N, 0);
}

// Round 3
// 618.140 us; speedup vs baseline: 5.3456x; 1.1657x over previous
//
#include <hip/hip_runtime.h>
#include <math.h>

// ---------------------------------------------------------------------------
// DDI_GraphTransformer: 2x TransformerConv(H=8, C=16, D=128), N=50000, E=800000
// R2: (a) Q/K/V/S GEMMs via bf16 MFMA (16x16x32), weights pre-transposed to
//     bf16 WT[n][k]; (b) node_attn with float4 gathers: 32 lanes/node, 4
//     channels/lane, width-4 shuffle head reduction, 1-exp online softmax.
// ---------------------------------------------------------------------------

#define HEADS 8
#define CH 16
#define DM 128
#define SCALE 0.25f

typedef __attribute__((ext_vector_type(8))) short short8;
typedef __attribute__((ext_vector_type(4))) float floatx4;

static __device__ __forceinline__ ushort f2bf(float f) {  // RNE fp32->bf16
    unsigned u = __float_as_uint(f);
    unsigned r = u + 0x7FFFu + ((u >> 16) & 1u);
    return (ushort)(r >> 16);
}

// ---------------- converters ------------------------------------------------
__global__ __launch_bounds__(256)
void cvt_x(const float* __restrict__ in, ushort* __restrict__ out, int n4)
{
    int i = blockIdx.x * 256 + threadIdx.x;
    if (i >= n4) return;
    float4 v = ((const float4*)in)[i];
    ushort4 s;
    s.x = f2bf(v.x); s.y = f2bf(v.y); s.z = f2bf(v.z); s.w = f2bf(v.w);
    ((ushort4*)out)[i] = s;
}

// WT[mat][n*128+k] = bf16(W[k*128+n]) for 4 weight matrices
__global__ __launch_bounds__(256)
void cvt_wT(const float* __restrict__ W0, const float* __restrict__ W1,
            const float* __restrict__ W2, const float* __restrict__ W3,
            ushort* __restrict__ WT)
{
    const float* W = (blockIdx.y == 0) ? W0 : (blockIdx.y == 1) ? W1
                   : (blockIdx.y == 2) ? W2 : W3;
    int idx = blockIdx.x * 256 + threadIdx.x;   // 0..16383
    int n = idx >> 7, k = idx & 127;
    WT[(size_t)blockIdx.y * 16384 + idx] = f2bf(W[k * 128 + n]);
}

// ---------------- bf16 MFMA GEMM: out = X @ W + b ---------------------------
// block = 256 thr = 4 waves; tile 128 rows x 64 cols; full K=128 in LDS.
// grid.x = ceil(N/128); grid.y = 8 (4 matrices x 2 col-halves)
#define AP 136   // LDS row pitch in shorts (128 + 8 pad -> 2-way=free banks)

__global__ __launch_bounds__(256)
void gemm_mfma(const ushort* __restrict__ Xb, const ushort* __restrict__ WT,
               const float* __restrict__ bq, const float* __restrict__ bk,
               const float* __restrict__ bv, const float* __restrict__ bsk,
               float* __restrict__ Qo, float* __restrict__ Ko,
               float* __restrict__ Vo, float* __restrict__ Yo, int N)
{
    __shared__ ushort As[128 * AP];   // [m][k]
    __shared__ ushort Bs[64 * AP];    // [n][k]  (W^T)

    const int by   = blockIdx.y;
    const int mat  = by >> 1;
    const int half = by & 1;
    const float* bias = (mat == 0) ? bq : (mat == 1) ? bk : (mat == 2) ? bv : bsk;
    float*       Out  = (mat == 0) ? Qo : (mat == 1) ? Ko : (mat == 2) ? Vo : Yo;
    const int row0 = blockIdx.x * 128;
    const int tid  = threadIdx.x;

    // stage A: 128 rows x 128 k bf16, 16B chunks (2048 chunks / 256 thr)
    #pragma unroll
    for (int i = 0; i < 8; ++i) {
        int id = tid + i * 256;
        int r = id >> 4, ch = id & 15;
        uint4 v = make_uint4(0, 0, 0, 0);
        if (row0 + r < N)
            v = *(const uint4*)(Xb + (size_t)(row0 + r) * DM + ch * 8);
        *(uint4*)(As + r * AP + ch * 8) = v;
    }
    // stage B: 64 n-rows x 128 k from WT[mat] starting at n = half*64
    const ushort* Wt = WT + (size_t)mat * 16384 + (size_t)(half * 64) * DM;
    #pragma unroll
    for (int i = 0; i < 4; ++i) {
        int id = tid + i * 256;
        int r = id >> 4, ch = id & 15;
        uint4 v = *(const uint4*)(Wt + (size_t)r * DM + ch * 8);
        *(uint4*)(Bs + r * AP + ch * 8) = v;
    }
    __syncthreads();

    const int lane = tid & 63, w = tid >> 6;
    const int mq = (w >> 1) * 64;     // wave's 64-row band
    const int nqw = (w & 1) * 32;     // wave's 32-col band
    const int lr = lane & 15, lq = lane >> 4;

    floatx4 acc[4][2] = {};
    #pragma unroll
    for (int ks = 0; ks < 4; ++ks) {
        const int koff = ks * 32 + lq * 8;
        short8 a[4], b[2];
        #pragma unroll
        for (int t = 0; t < 4; ++t)
            a[t] = *(const short8*)(As + (mq + t * 16 + lr) * AP + koff);
        #pragma unroll
        for (int t = 0; t < 2; ++t)
            b[t] = *(const short8*)(Bs + (nqw + t * 16 + lr) * AP + koff);
        #pragma unroll
        for (int mt = 0; mt < 4; ++mt)
            #pragma unroll
            for (int nt = 0; nt < 2; ++nt)
                acc[mt][nt] = __builtin_amdgcn_mfma_f32_16x16x32_bf16(
                    a[mt], b[nt], acc[mt][nt], 0, 0, 0);
    }

    // epilogue: C/D layout col=lane&15, row=(lane>>4)*4+reg  [m89-verified]
    #pragma unroll
    for (int nt = 0; nt < 2; ++nt) {
        const int col = half * 64 + nqw + nt * 16 + lr;
        const float bcol = bias[col];
        #pragma unroll
        for (int mt = 0; mt < 4; ++mt) {
            const int rbase = row0 + mq + mt * 16 + lq * 4;
            #pragma unroll
            for (int r = 0; r < 4; ++r) {
                const int row = rbase + r;
                if (row < N)
                    Out[(size_t)row * DM + col] = acc[mt][nt][r] + bcol;
            }
        }
    }
}

// ---------------- CSR build: histogram -> scan -> scatter --------------------
__global__ __launch_bounds__(256)
void hist_k(const int* __restrict__ dst, int* __restrict__ counts, int E)
{
    int e = blockIdx.x * blockDim.x + threadIdx.x;
    if (e < E) atomicAdd(&counts[dst[e]], 1);
}

__global__ __launch_bounds__(1024)
void scan_k(const int* __restrict__ counts, int* __restrict__ rowptr, int N)
{
    __shared__ int sdata[1024];
    const int t = threadIdx.x;
    const int chunk = (N + 1023) / 1024;
    const int begin = t * chunk;
    const int end   = min(begin + chunk, N);
    int sum = 0;
    for (int i = begin; i < end; ++i) sum += counts[i];
    sdata[t] = sum;
    __syncthreads();
    for (int off = 1; off < 1024; off <<= 1) {
        int v = (t >= off) ? sdata[t - off] : 0;
        __syncthreads();
        if (t >= off) sdata[t] += v;
        __syncthreads();
    }
    int run = (t == 0) ? 0 : sdata[t - 1];
    for (int i = begin; i < end; ++i) {
        rowptr[i] = run;
        run += counts[i];
    }
    if (t == 0) rowptr[N] = sdata[1023];
}

__global__ __launch_bounds__(256)
void scatter_k(const int* __restrict__ src, const int* __restrict__ dst,
               int* __restrict__ cursor, int* __restrict__ esrc, int E)
{
    int e = blockIdx.x * blockDim.x + threadIdx.x;
    if (e >= E) return;
    int pos = atomicAdd(&cursor[dst[e]], 1);
    esrc[pos] = src[e];
}

// ---------------- fused per-node attention (32 lanes/node, float4/lane) ------
__global__ __launch_bounds__(256)
void node_attn(const float* __restrict__ Q, const float* __restrict__ K,
               const float* __restrict__ V,
               const int* __restrict__ rowptr, const int* __restrict__ esrc,
               float* __restrict__ Y, int N, int relu)
{
    const int nid = blockIdx.x * 8 + (threadIdx.x >> 5);
    if (nid >= N) return;
    const int c4 = (threadIdx.x & 31) * 4;      // channel base; head = c4>>4
    const float4 q = *(const float4*)(Q + (size_t)nid * DM + c4);
    const int beg = rowptr[nid], end = rowptr[nid + 1];

    float m = -INFINITY, l = 0.f;
    float ax = 0.f, ay = 0.f, az = 0.f, aw = 0.f;
    for (int i = beg; i < end; ++i) {
        const int s = esrc[i];
        const float4 k = *(const float4*)(K + (size_t)s * DM + c4);
        const float4 v = *(const float4*)(V + (size_t)s * DM + c4);
        float p = q.x * k.x + q.y * k.y + q.z * k.z + q.w * k.w;
        p += __shfl_xor(p, 1, 4);               // reduce over the head's
        p += __shfl_xor(p, 2, 4);               // 4 lanes (16 channels)
        p *= SCALE;
        if (p <= m) {                            // common case: 1 exp
            const float wgt = __expf(p - m);
            l += wgt;
            ax += wgt * v.x; ay += wgt * v.y; az += wgt * v.z; aw += wgt * v.w;
        } else {                                 // new max: rescale
            const float r = __expf(m - p);       // exp(-inf)=0 on first edge
            l = l * r + 1.f;
            ax = ax * r + v.x; ay = ay * r + v.y;
            az = az * r + v.z; aw = aw * r + v.w;
            m = p;
        }
    }
    const float inv = (l > 0.f) ? 1.f / l : 0.f;
    float4 y = *(float4*)(Y + (size_t)nid * DM + c4);
    y.x += ax * inv; y.y += ay * inv; y.z += az * inv; y.w += aw * inv;
    if (relu) {
        y.x = fmaxf(y.x, 0.f); y.y = fmaxf(y.y, 0.f);
        y.z = fmaxf(y.z, 0.f); y.w = fmaxf(y.w, 0.f);
    }
    *(float4*)(Y + (size_t)nid * DM + c4) = y;
}

// ---------------------------------------------------------------------------
extern "C" void kernel_launch(void* const* d_in, const int* in_sizes, int n_in,
                              void* d_out, int out_size, void* d_ws, size_t ws_size,
                              hipStream_t stream)
{
    const float* x   = (const float*)d_in[0];
    const int* eidx  = (const int*)d_in[1];
    const float* qw0 = (const float*)d_in[3];  const float* qb0 = (const float*)d_in[4];
    const float* kw0 = (const float*)d_in[5];  const float* kb0 = (const float*)d_in[6];
    const float* vw0 = (const float*)d_in[7];  const float* vb0 = (const float*)d_in[8];
    const float* sw0 = (const float*)d_in[9];  const float* sb0 = (const float*)d_in[10];
    const float* qw1 = (const float*)d_in[11]; const float* qb1 = (const float*)d_in[12];
    const float* kw1 = (const float*)d_in[13]; const float* kb1 = (const float*)d_in[14];
    const float* vw1 = (const float*)d_in[15]; const float* vb1 = (const float*)d_in[16];
    const float* sw1 = (const float*)d_in[17]; const float* sb1 = (const float*)d_in[18];

    const int N = in_sizes[0] / DM;
    const int E = in_sizes[1] / 2;
    const int* src = eidx;
    const int* dst = eidx + E;

    // workspace: Q,K,V,H1 [N*128 f32] | Xb [N*128 bf16] | WT [4*16384 bf16]
    //            | counts[N] rowptr[N+1] cursor[N] esrc[E]
    float* ws  = (float*)d_ws;
    size_t nd  = (size_t)N * DM;
    float* Q   = ws;
    float* K   = Q + nd;
    float* V   = K + nd;
    float* H1  = V + nd;
    ushort* Xb = (ushort*)(H1 + nd);
    ushort* WT = Xb + nd;
    int* counts = (int*)(WT + 4 * 16384);
    int* rowptr = counts + N;
    int* cursor = rowptr + (N + 1);
    int* esrc   = cursor + N;
    float* out  = (float*)d_out;

    // ---- CSR build (shared by both layers) ----
    hipMemsetAsync(counts, 0, (size_t)N * sizeof(int), stream);
    hist_k<<<(E + 255) / 256, 256, 0, stream>>>(dst, counts, E);
    scan_k<<<1, 1024, 0, stream>>>(counts, rowptr, N);
    hipMemcpyAsync(cursor, rowptr, (size_t)N * sizeof(int),
                   hipMemcpyDeviceToDevice, stream);
    scatter_k<<<(E + 255) / 256, 256, 0, stream>>>(src, dst, cursor, esrc, E);

    const int n4 = N * (DM / 4);
    dim3 ggrid((N + 127) / 128, 8);

    // ---- layer 1: x -> H1 (relu) ----
    cvt_x<<<(n4 + 255) / 256, 256, 0, stream>>>(x, Xb, n4);
    cvt_wT<<<dim3(64, 4), 256, 0, stream>>>(qw0, kw0, vw0, sw0, WT);
    gemm_mfma<<<ggrid, 256, 0, stream>>>(Xb, WT, qb0, kb0, vb0, sb0,
                                         Q, K, V, H1, N);
    node_attn<<<(N + 7) / 8, 256, 0, stream>>>(Q, K, V, rowptr, esrc, H1, N, 1);

    // ---- layer 2: H1 -> out ----
    cvt_x<<<(n4 + 255) / 256, 256, 0, stream>>>(H1, Xb, n4);
    cvt_wT<<<dim3(64, 4), 256, 0, stream>>>(qw1, kw1, vw1, sw1, WT);
    gemm_mfma<<<ggrid, 256, 0, stream>>>(Xb, WT, qb1, kb1, vb1, sb1,
                                         Q, K, V, out, N);
    node_attn<<<(N + 7) / 8, 256, 0, stream>>>(Q, K, V, rowptr, esrc, out, N, 0);
}